// Round 14
// baseline (54.783 us; speedup 1.0000x reference)
//
#include <hip/hip_runtime.h>

// LVAE_shGLM encoder, fused bf16-MFMA implementation for gfx950.
// Round 14: r13 with the register ceiling fixed. r12/r13 both spilled because
// the unified gfx950 reg file is split by accum_offset: (512,4) caps at 128,
// acc[2][2]=64 AGPR leaves 64 arch VGPRs < the ~75 the 2-B-frag pipelined
// loop needs -> scratch traffic (WRITE 37MB). launch_bounds(512,3) caps at
// ~170: 64 AGPR + ~75 arch fits, no spill; 3 waves/SIMD -> 1 block/CU
// (8 waves). r8->r9 measured the occupancy curve as shallow (+3% for 2x), so
// this trades cheap occupancy for the A-reuse LDS halving r13 aimed at.
//
//   h_mid  = relu(windows @ W1 + b1)   windows[t,k] = pad[t+k]
//   mu_mid = h_mid @ W2 + b2           -> out[:, 0:4]
//   h_leaf = relu(h_mid @ Wl1 + bl1)
//   mu_leaf= h_leaf @ Wl2 + bl2        -> out[:, 4:20]

typedef __bf16 bf16;
typedef __bf16 bf16x8 __attribute__((ext_vector_type(8)));
typedef float  f32x4  __attribute__((ext_vector_type(4)));
typedef float  f32x16 __attribute__((ext_vector_type(16)));

constexpr int T_DATA = 100000;
constexpr int T_V    = 100;
constexpr int WIN    = 199;   // 2*T_V - 1
constexpr int HID    = 256;
constexpr int BT     = 128;   // timesteps per block
constexpr int HSTR   = 264;   // h-buffer row stride (elems); 528B (16B-aligned)
constexpr int VLEN   = 352;   // window span: 128 rows + 207 max k + 8 frag + pad
constexpr int VSTR   = 360;   // Vdup row stride (720B, 16B-aligned)

// ws layout in bf16 elements (written by pack_weights), 1KB groups:
//   [0*512     ..) PW1_32   13 kt(K=16) x 8 nt(32 cols)  = 104 groups (k>=199 zeroed)
//   [104*512   ..) PWL1_32  16 kt x 8 nt                 = 128 groups
//   [232*512   ..) PW2      8 kt(K=32), 16x16 frag, cols 0..3 real
//   [240*512   ..) PWL2     8 kt(K=32), 16x16 frag, 16 cols
constexpr int PWL1_OFF = 104 * 512;
constexpr int PW2_OFF  = 232 * 512;
constexpr int PWL2_OFF = 240 * 512;   // total 248 KB <= ws

__global__ void pack_weights(const float* __restrict__ W1, const float* __restrict__ W2,
                             const float* __restrict__ Wl1, const float* __restrict__ Wl2,
                             bf16* __restrict__ ws) {
  const int gid  = blockIdx.x * blockDim.x + threadIdx.x;  // [0, 15872)
  const int lane = gid & 63;
  const int grp  = gid >> 6;        // [0, 248)
  bf16x8 v;
  if (grp < 104) {                  // PW1_32: 32x32x16 B frag: col=lane&31, k=(lane>>5)*8+j
    const int kt = grp >> 3, nt = grp & 7, n = nt * 32 + (lane & 31);
#pragma unroll
    for (int j = 0; j < 8; ++j) {
      const int k = kt * 16 + (lane >> 5) * 8 + j;
      v[j] = (k < WIN) ? (bf16)W1[k * HID + n] : (bf16)0.0f;
    }
  } else if (grp < 232) {           // PWL1_32
    const int q = grp - 104;
    const int kt = q >> 3, nt = q & 7, n = nt * 32 + (lane & 31);
#pragma unroll
    for (int j = 0; j < 8; ++j) {
      const int k = kt * 16 + (lane >> 5) * 8 + j;
      v[j] = (bf16)Wl1[k * HID + n];
    }
  } else if (grp < 240) {           // PW2: 16x16x32 frag: col=lane&15, k=(lane>>4)*8+j
    const int kt = grp - 232, m = lane & 15;
#pragma unroll
    for (int j = 0; j < 8; ++j) {
      const int k = kt * 32 + (lane >> 4) * 8 + j;
      v[j] = (m < 4) ? (bf16)W2[k * 4 + m] : (bf16)0.0f;
    }
  } else {                          // PWL2
    const int kt = grp - 240, m = lane & 15;
#pragma unroll
    for (int j = 0; j < 8; ++j) {
      const int k = kt * 32 + (lane >> 4) * 8 + j;
      v[j] = (bf16)Wl2[k * 16 + m];
    }
  }
  *reinterpret_cast<bf16x8*>(ws + (size_t)gid * 8) = v;
}

__global__ __launch_bounds__(512, 3) void fused_enc(
    const float* __restrict__ V, const float* __restrict__ b1,
    const float* __restrict__ b2, const float* __restrict__ bl1,
    const float* __restrict__ bl2, const bf16* __restrict__ ws,
    float* __restrict__ out) {
  __shared__ bf16 Vdup[8][VSTR];    // 5.8 KB: Vdup[p][q] = pad[t0-99+q+p]
  __shared__ bf16 hbuf[BT * HSTR];  // 67.6 KB: h_mid, then h_leaf (WAR barrier)

  const int tid  = threadIdx.x;
  const int lane = tid & 63;
  const int w    = tid >> 6;            // wave id [0,8)
  const int wr   = w >> 2;              // row half: rows wr*64 .. wr*64+63
  const int wc   = w & 3;               // col stripe: cols wc*64 .. wc*64+63
  const int c5   = lane & 31;           // 32x32 frag col/row index
  const int hi   = lane >> 5;           // 32x32 frag k-half
  const int m    = lane & 15;           // 16x16 frag index
  const int g    = lane >> 4;           // 16x16 k-group
  const long t0  = (long)blockIdx.x * BT;

  // ---- 1. stage 8 shifted bf16 window copies ----
  for (int c = tid; c < 8 * VLEN; c += 512) {
    const int p = c / VLEN, q = c - p * VLEN;
    const long src = t0 + q + p - (T_V - 1);
    const float v = (src >= 0 && src < T_DATA) ? V[src] : 0.0f;
    Vdup[p][q] = (bf16)v;
  }
  __syncthreads();   // B0

  // A-frag element s = (wr*64 + rt*32 + c5) + kt*16 + hi*8 + j; s mod 8 = lane&7
  // (wr*64, rt*32 are 0 mod 8) -> copy p = lane&7 gives one aligned b128 read.
  const int p  = lane & 7;
  const int qb = (c5 + hi * 8) - p + wr * 64;  // aligned base within Vdup row p
  const bf16* vrow = &Vdup[p][0];

  f32x16 acc[2][2];   // [rt][c]: rows wr*64+rt*32+.., cols wc*64+c*32+c5
#pragma unroll
  for (int rt = 0; rt < 2; ++rt)
#pragma unroll
    for (int c = 0; c < 2; ++c) acc[rt][c] = (f32x16){};

  // ---- 2. GEMM1: h_mid(pre) = windows @ W1, 13 kt of K=16 ----
#pragma unroll
  for (int kt = 0; kt < 13; ++kt) {
    bf16x8 bfr[2];
#pragma unroll
    for (int c = 0; c < 2; ++c)
      bfr[c] = *reinterpret_cast<const bf16x8*>(
          ws + (size_t)(kt * 8 + wc * 2 + c) * 512 + lane * 8);
#pragma unroll
    for (int rt = 0; rt < 2; ++rt) {
      const bf16x8 a = *reinterpret_cast<const bf16x8*>(vrow + qb + rt * 32 + kt * 16);
#pragma unroll
      for (int c = 0; c < 2; ++c)
        acc[rt][c] = __builtin_amdgcn_mfma_f32_32x32x16_bf16(a, bfr[c], acc[rt][c], 0, 0, 0);
    }
  }

  // ---- 3. h_mid epilogue: bias+relu -> hbuf ----
  // C/D 32x32 layout: col = lane&31, row = (r&3) + 8*(r>>2) + 4*(lane>>5)
#pragma unroll
  for (int c = 0; c < 2; ++c) {
    const int col = wc * 64 + c * 32 + c5;
    const float bb = b1[col];
#pragma unroll
    for (int rt = 0; rt < 2; ++rt)
#pragma unroll
      for (int r = 0; r < 16; ++r) {
        const int row = wr * 64 + rt * 32 + (r & 3) + 8 * (r >> 2) + 4 * hi;
        hbuf[row * HSTR + col] = (bf16)fmaxf(acc[rt][c][r] + bb, 0.0f);
      }
  }
  __syncthreads();   // B1: h_mid visible

  // ---- 4. GEMM3: h_leaf(pre) = h_mid @ Wl1, 16 kt of K=16 ----
#pragma unroll
  for (int rt = 0; rt < 2; ++rt)
#pragma unroll
    for (int c = 0; c < 2; ++c) acc[rt][c] = (f32x16){};
#pragma unroll
  for (int kt = 0; kt < 16; ++kt) {
    bf16x8 bfr[2];
#pragma unroll
    for (int c = 0; c < 2; ++c)
      bfr[c] = *reinterpret_cast<const bf16x8*>(
          ws + PWL1_OFF + (size_t)(kt * 8 + wc * 2 + c) * 512 + lane * 8);
    const int koff = kt * 16 + hi * 8;
#pragma unroll
    for (int rt = 0; rt < 2; ++rt) {
      const bf16x8 a = *reinterpret_cast<const bf16x8*>(
          &hbuf[(wr * 64 + rt * 32 + c5) * HSTR + koff]);
#pragma unroll
      for (int c = 0; c < 2; ++c)
        acc[rt][c] = __builtin_amdgcn_mfma_f32_32x32x16_bf16(a, bfr[c], acc[rt][c], 0, 0, 0);
    }
  }

  // ---- 4b. mu_mid: wave w handles rows w*16 .. w*16+15 (reads h_mid) ----
  f32x4 mu = {0.f, 0.f, 0.f, 0.f};
#pragma unroll
  for (int kt = 0; kt < 8; ++kt) {
    const bf16x8 a = *reinterpret_cast<const bf16x8*>(
        &hbuf[(w * 16 + m) * HSTR + kt * 32 + g * 8]);
    const bf16x8 b = *reinterpret_cast<const bf16x8*>(
        ws + PW2_OFF + (size_t)kt * 512 + lane * 8);
    mu = __builtin_amdgcn_mfma_f32_16x16x32_bf16(a, b, mu, 0, 0, 0);
  }
  {
    const float b2v = (m < 4) ? b2[m] : 0.0f;
#pragma unroll
    for (int j = 0; j < 4; ++j) {       // C 16x16: col=lane&15, row=(lane>>4)*4+reg
      const long t = t0 + w * 16 + g * 4 + j;
      if (t < T_DATA && m < 4) out[t * 20 + m] = mu[j] + b2v;
    }
  }
  __syncthreads();   // B2 (WAR): all h_mid reads done before h_leaf overwrite

  // ---- 5. h_leaf epilogue: bias+relu -> hbuf ----
#pragma unroll
  for (int c = 0; c < 2; ++c) {
    const int col = wc * 64 + c * 32 + c5;
    const float bb = bl1[col];
#pragma unroll
    for (int rt = 0; rt < 2; ++rt)
#pragma unroll
      for (int r = 0; r < 16; ++r) {
        const int row = wr * 64 + rt * 32 + (r & 3) + 8 * (r >> 2) + 4 * hi;
        hbuf[row * HSTR + col] = (bf16)fmaxf(acc[rt][c][r] + bb, 0.0f);
      }
  }
  __syncthreads();   // B3: h_leaf visible

  // ---- 6. mu_leaf: wave w handles rows w*16 .. w*16+15 ----
  mu = (f32x4){0.f, 0.f, 0.f, 0.f};
#pragma unroll
  for (int kq = 0; kq < 8; ++kq) {
    const bf16x8 a = *reinterpret_cast<const bf16x8*>(
        &hbuf[(w * 16 + m) * HSTR + kq * 32 + g * 8]);
    const bf16x8 b = *reinterpret_cast<const bf16x8*>(
        ws + PWL2_OFF + (size_t)kq * 512 + lane * 8);
    mu = __builtin_amdgcn_mfma_f32_16x16x32_bf16(a, b, mu, 0, 0, 0);
  }
  {
    const float blv = bl2[m];
#pragma unroll
    for (int j = 0; j < 4; ++j) {
      const long t = t0 + w * 16 + g * 4 + j;
      if (t < T_DATA) out[t * 20 + 4 + m] = mu[j] + blv;
    }
  }
}

extern "C" void kernel_launch(void* const* d_in, const int* in_sizes, int n_in,
                              void* d_out, int out_size, void* d_ws, size_t ws_size,
                              hipStream_t stream) {
  const float* V   = (const float*)d_in[0];
  const float* W1  = (const float*)d_in[1];
  const float* b1  = (const float*)d_in[2];
  const float* W2  = (const float*)d_in[3];
  const float* b2  = (const float*)d_in[4];
  const float* Wl1 = (const float*)d_in[5];
  const float* bl1 = (const float*)d_in[6];
  const float* Wl2 = (const float*)d_in[7];
  const float* bl2 = (const float*)d_in[8];
  bf16* ws = (bf16*)d_ws;   // needs 253952 bytes
  float* out = (float*)d_out;

  pack_weights<<<62, 256, 0, stream>>>(W1, W2, Wl1, Wl2, ws);

  const int grid = (T_DATA + BT - 1) / BT;   // 782
  fused_enc<<<grid, 512, 0, stream>>>(V, b1, b2, bl1, bl2, ws, out);
}

// Round 15
// 47.060 us; speedup vs baseline: 1.1641x; 1.1641x over previous
//
#include <hip/hip_runtime.h>

// LVAE_shGLM encoder, fused bf16-MFMA implementation for gfx950.
// Round 15: the A-reuse experiment, finally uncontaminated. Ledger: r12
// spilled (acc128+arch>128), r13 spilled (cap128, full unroll hoisted ~75
// arch), r14 fit via (512,3) but dropped to 1 block/CU and lost the ~12us
// co-residency benefit (r11 40.5 vs r14 52.4, same LDS). This round: r13's
// 2x4 wave grid (acc[2][2]=64 AGPR, A ds_read_b128 feeds 2 MFMAs) +
// launch_bounds(512,4) + #pragma unroll 2 on the kt loops to cap the
// scheduler's load-hoisting live-set at ~116 regs -> no spill, 4 waves/SIMD,
// 2 blocks/CU. Gates: WRITE=7.8MB, VGPR<=64, Occ>=26%.
//
//   h_mid  = relu(windows @ W1 + b1)   windows[t,k] = pad[t+k]
//   mu_mid = h_mid @ W2 + b2           -> out[:, 0:4]
//   h_leaf = relu(h_mid @ Wl1 + bl1)
//   mu_leaf= h_leaf @ Wl2 + bl2        -> out[:, 4:20]

typedef __bf16 bf16;
typedef __bf16 bf16x8 __attribute__((ext_vector_type(8)));
typedef float  f32x4  __attribute__((ext_vector_type(4)));
typedef float  f32x16 __attribute__((ext_vector_type(16)));

constexpr int T_DATA = 100000;
constexpr int T_V    = 100;
constexpr int WIN    = 199;   // 2*T_V - 1
constexpr int HID    = 256;
constexpr int BT     = 128;   // timesteps per block
constexpr int HSTR   = 264;   // h-buffer row stride (elems); 528B (16B-aligned)
constexpr int VLEN   = 352;   // window span: 128 rows + 207 max k + 8 frag + pad
constexpr int VSTR   = 360;   // Vdup row stride (720B, 16B-aligned)

// ws layout in bf16 elements (written by pack_weights), 1KB groups:
//   [0*512     ..) PW1_32   13 kt(K=16) x 8 nt(32 cols)  = 104 groups (k>=199 zeroed)
//   [104*512   ..) PWL1_32  16 kt x 8 nt                 = 128 groups
//   [232*512   ..) PW2      8 kt(K=32), 16x16 frag, cols 0..3 real
//   [240*512   ..) PWL2     8 kt(K=32), 16x16 frag, 16 cols
constexpr int PWL1_OFF = 104 * 512;
constexpr int PW2_OFF  = 232 * 512;
constexpr int PWL2_OFF = 240 * 512;   // total 248 KB <= ws

__global__ void pack_weights(const float* __restrict__ W1, const float* __restrict__ W2,
                             const float* __restrict__ Wl1, const float* __restrict__ Wl2,
                             bf16* __restrict__ ws) {
  const int gid  = blockIdx.x * blockDim.x + threadIdx.x;  // [0, 15872)
  const int lane = gid & 63;
  const int grp  = gid >> 6;        // [0, 248)
  bf16x8 v;
  if (grp < 104) {                  // PW1_32: 32x32x16 B frag: col=lane&31, k=(lane>>5)*8+j
    const int kt = grp >> 3, nt = grp & 7, n = nt * 32 + (lane & 31);
#pragma unroll
    for (int j = 0; j < 8; ++j) {
      const int k = kt * 16 + (lane >> 5) * 8 + j;
      v[j] = (k < WIN) ? (bf16)W1[k * HID + n] : (bf16)0.0f;
    }
  } else if (grp < 232) {           // PWL1_32
    const int q = grp - 104;
    const int kt = q >> 3, nt = q & 7, n = nt * 32 + (lane & 31);
#pragma unroll
    for (int j = 0; j < 8; ++j) {
      const int k = kt * 16 + (lane >> 5) * 8 + j;
      v[j] = (bf16)Wl1[k * HID + n];
    }
  } else if (grp < 240) {           // PW2: 16x16x32 frag: col=lane&15, k=(lane>>4)*8+j
    const int kt = grp - 232, m = lane & 15;
#pragma unroll
    for (int j = 0; j < 8; ++j) {
      const int k = kt * 32 + (lane >> 4) * 8 + j;
      v[j] = (m < 4) ? (bf16)W2[k * 4 + m] : (bf16)0.0f;
    }
  } else {                          // PWL2
    const int kt = grp - 240, m = lane & 15;
#pragma unroll
    for (int j = 0; j < 8; ++j) {
      const int k = kt * 32 + (lane >> 4) * 8 + j;
      v[j] = (bf16)Wl2[k * 16 + m];
    }
  }
  *reinterpret_cast<bf16x8*>(ws + (size_t)gid * 8) = v;
}

__global__ __launch_bounds__(512, 4) void fused_enc(
    const float* __restrict__ V, const float* __restrict__ b1,
    const float* __restrict__ b2, const float* __restrict__ bl1,
    const float* __restrict__ bl2, const bf16* __restrict__ ws,
    float* __restrict__ out) {
  __shared__ bf16 Vdup[8][VSTR];    // 5.8 KB: Vdup[p][q] = pad[t0-99+q+p]
  __shared__ bf16 hbuf[BT * HSTR];  // 67.6 KB: h_mid, then h_leaf (WAR barrier)
  // total 73344 B -> 2 blocks/CU

  const int tid  = threadIdx.x;
  const int lane = tid & 63;
  const int w    = tid >> 6;            // wave id [0,8)
  const int wr   = w >> 2;              // row half: rows wr*64 .. wr*64+63
  const int wc   = w & 3;               // col stripe: cols wc*64 .. wc*64+63
  const int c5   = lane & 31;           // 32x32 frag col/row index
  const int hi   = lane >> 5;           // 32x32 frag k-half
  const int m    = lane & 15;           // 16x16 frag index
  const int g    = lane >> 4;           // 16x16 k-group
  const long t0  = (long)blockIdx.x * BT;

  // ---- 1. stage 8 shifted bf16 window copies ----
  for (int c = tid; c < 8 * VLEN; c += 512) {
    const int p = c / VLEN, q = c - p * VLEN;
    const long src = t0 + q + p - (T_V - 1);
    const float v = (src >= 0 && src < T_DATA) ? V[src] : 0.0f;
    Vdup[p][q] = (bf16)v;
  }
  __syncthreads();   // B0

  // A-frag element s = (wr*64 + rt*32 + c5) + kt*16 + hi*8 + j; s mod 8 = lane&7
  // (wr*64, rt*32 are 0 mod 8) -> copy p = lane&7 gives one aligned b128 read.
  const int p  = lane & 7;
  const int qb = (c5 + hi * 8) - p + wr * 64;  // aligned base within Vdup row p
  const bf16* vrow = &Vdup[p][0];

  f32x16 acc[2][2];   // [rt][c]: rows wr*64+rt*32+.., cols wc*64+c*32+c5
#pragma unroll
  for (int rt = 0; rt < 2; ++rt)
#pragma unroll
    for (int c = 0; c < 2; ++c) acc[rt][c] = (f32x16){};

  // ---- 2. GEMM1: h_mid(pre) = windows @ W1, 13 kt of K=16 ----
  // unroll 2: limits load-hoisting live-set so (512,4)'s 128-reg cap holds.
#pragma unroll 2
  for (int kt = 0; kt < 13; ++kt) {
    bf16x8 bfr[2];
#pragma unroll
    for (int c = 0; c < 2; ++c)
      bfr[c] = *reinterpret_cast<const bf16x8*>(
          ws + (size_t)(kt * 8 + wc * 2 + c) * 512 + lane * 8);
#pragma unroll
    for (int rt = 0; rt < 2; ++rt) {
      const bf16x8 a = *reinterpret_cast<const bf16x8*>(vrow + qb + rt * 32 + kt * 16);
#pragma unroll
      for (int c = 0; c < 2; ++c)
        acc[rt][c] = __builtin_amdgcn_mfma_f32_32x32x16_bf16(a, bfr[c], acc[rt][c], 0, 0, 0);
    }
  }

  // ---- 3. h_mid epilogue: bias+relu -> hbuf ----
  // C/D 32x32 layout: col = lane&31, row = (r&3) + 8*(r>>2) + 4*(lane>>5)
#pragma unroll
  for (int c = 0; c < 2; ++c) {
    const int col = wc * 64 + c * 32 + c5;
    const float bb = b1[col];
#pragma unroll
    for (int rt = 0; rt < 2; ++rt)
#pragma unroll
      for (int r = 0; r < 16; ++r) {
        const int row = wr * 64 + rt * 32 + (r & 3) + 8 * (r >> 2) + 4 * hi;
        hbuf[row * HSTR + col] = (bf16)fmaxf(acc[rt][c][r] + bb, 0.0f);
      }
  }
  __syncthreads();   // B1: h_mid visible

  // ---- 4. GEMM3: h_leaf(pre) = h_mid @ Wl1, 16 kt of K=16 ----
#pragma unroll
  for (int rt = 0; rt < 2; ++rt)
#pragma unroll
    for (int c = 0; c < 2; ++c) acc[rt][c] = (f32x16){};
#pragma unroll 2
  for (int kt = 0; kt < 16; ++kt) {
    bf16x8 bfr[2];
#pragma unroll
    for (int c = 0; c < 2; ++c)
      bfr[c] = *reinterpret_cast<const bf16x8*>(
          ws + PWL1_OFF + (size_t)(kt * 8 + wc * 2 + c) * 512 + lane * 8);
    const int koff = kt * 16 + hi * 8;
#pragma unroll
    for (int rt = 0; rt < 2; ++rt) {
      const bf16x8 a = *reinterpret_cast<const bf16x8*>(
          &hbuf[(wr * 64 + rt * 32 + c5) * HSTR + koff]);
#pragma unroll
      for (int c = 0; c < 2; ++c)
        acc[rt][c] = __builtin_amdgcn_mfma_f32_32x32x16_bf16(a, bfr[c], acc[rt][c], 0, 0, 0);
    }
  }

  // ---- 4b. mu_mid: wave w handles rows w*16 .. w*16+15 (reads h_mid) ----
  f32x4 mu = {0.f, 0.f, 0.f, 0.f};
#pragma unroll 2
  for (int kt = 0; kt < 8; ++kt) {
    const bf16x8 a = *reinterpret_cast<const bf16x8*>(
        &hbuf[(w * 16 + m) * HSTR + kt * 32 + g * 8]);
    const bf16x8 b = *reinterpret_cast<const bf16x8*>(
        ws + PW2_OFF + (size_t)kt * 512 + lane * 8);
    mu = __builtin_amdgcn_mfma_f32_16x16x32_bf16(a, b, mu, 0, 0, 0);
  }
  {
    const float b2v = (m < 4) ? b2[m] : 0.0f;
#pragma unroll
    for (int j = 0; j < 4; ++j) {       // C 16x16: col=lane&15, row=(lane>>4)*4+reg
      const long t = t0 + w * 16 + g * 4 + j;
      if (t < T_DATA && m < 4) out[t * 20 + m] = mu[j] + b2v;
    }
  }
  __syncthreads();   // B2 (WAR): all h_mid reads done before h_leaf overwrite

  // ---- 5. h_leaf epilogue: bias+relu -> hbuf ----
#pragma unroll
  for (int c = 0; c < 2; ++c) {
    const int col = wc * 64 + c * 32 + c5;
    const float bb = bl1[col];
#pragma unroll
    for (int rt = 0; rt < 2; ++rt)
#pragma unroll
      for (int r = 0; r < 16; ++r) {
        const int row = wr * 64 + rt * 32 + (r & 3) + 8 * (r >> 2) + 4 * hi;
        hbuf[row * HSTR + col] = (bf16)fmaxf(acc[rt][c][r] + bb, 0.0f);
      }
  }
  __syncthreads();   // B3: h_leaf visible

  // ---- 6. mu_leaf: wave w handles rows w*16 .. w*16+15 ----
  mu = (f32x4){0.f, 0.f, 0.f, 0.f};
#pragma unroll 2
  for (int kq = 0; kq < 8; ++kq) {
    const bf16x8 a = *reinterpret_cast<const bf16x8*>(
        &hbuf[(w * 16 + m) * HSTR + kq * 32 + g * 8]);
    const bf16x8 b = *reinterpret_cast<const bf16x8*>(
        ws + PWL2_OFF + (size_t)kq * 512 + lane * 8);
    mu = __builtin_amdgcn_mfma_f32_16x16x32_bf16(a, b, mu, 0, 0, 0);
  }
  {
    const float blv = bl2[m];
#pragma unroll
    for (int j = 0; j < 4; ++j) {
      const long t = t0 + w * 16 + g * 4 + j;
      if (t < T_DATA) out[t * 20 + 4 + m] = mu[j] + blv;
    }
  }
}

extern "C" void kernel_launch(void* const* d_in, const int* in_sizes, int n_in,
                              void* d_out, int out_size, void* d_ws, size_t ws_size,
                              hipStream_t stream) {
  const float* V   = (const float*)d_in[0];
  const float* W1  = (const float*)d_in[1];
  const float* b1  = (const float*)d_in[2];
  const float* W2  = (const float*)d_in[3];
  const float* b2  = (const float*)d_in[4];
  const float* Wl1 = (const float*)d_in[5];
  const float* bl1 = (const float*)d_in[6];
  const float* Wl2 = (const float*)d_in[7];
  const float* bl2 = (const float*)d_in[8];
  bf16* ws = (bf16*)d_ws;   // needs 253952 bytes
  float* out = (float*)d_out;

  pack_weights<<<62, 256, 0, stream>>>(W1, W2, Wl1, Wl2, ws);

  const int grid = (T_DATA + BT - 1) / BT;   // 782
  fused_enc<<<grid, 512, 0, stream>>>(V, b1, b2, bl1, bl2, ws, out);
}

// Round 16
// 45.677 us; speedup vs baseline: 1.1994x; 1.0303x over previous
//
#include <hip/hip_runtime.h>

// LVAE_shGLM encoder, fused bf16-MFMA implementation for gfx950.
// Round 16: co-residency depth 3. r15 falsified LDS-throughput (halved A-reads,
// clean gates, no gain); r11-vs-r14 measured co-residency at ~12us/step (2 vs 1
// blocks/CU). This round: r10's verified BT=64 32x32 shape with a SINGLE hbuf
// (r9 4-barrier WAR structure) -> 37.6 KB LDS, launch_bounds(512,6) (cap 85:
// 52 arch + 32 acc = 84 fits) -> 3 blocks/CU, 24 waves. Gates: WRITE 7.8MB,
// VGPR<=53 arch, Occ>=35%.
//
//   h_mid  = relu(windows @ W1 + b1)   windows[t,k] = pad[t+k]
//   mu_mid = h_mid @ W2 + b2           -> out[:, 0:4]
//   h_leaf = relu(h_mid @ Wl1 + bl1)
//   mu_leaf= h_leaf @ Wl2 + bl2        -> out[:, 4:20]

typedef __bf16 bf16;
typedef __bf16 bf16x8 __attribute__((ext_vector_type(8)));
typedef float  f32x4  __attribute__((ext_vector_type(4)));
typedef float  f32x16 __attribute__((ext_vector_type(16)));

constexpr int T_DATA = 100000;
constexpr int T_V    = 100;
constexpr int WIN    = 199;   // 2*T_V - 1
constexpr int HID    = 256;
constexpr int BT     = 64;    // timesteps per block
constexpr int HSTR   = 264;   // h-buffer row stride (elems); 528B (16B-aligned)
constexpr int VLEN   = 288;   // window span: 64 rows + 207 max k + 8 frag + pad
constexpr int VSTR   = 296;   // Vdup row stride (592B, 16B-aligned)

// ws layout in bf16 elements (written by pack_weights), 1KB groups:
//   [0*512     ..) PW1_32   13 kt(K=16) x 8 nt(32 cols)  = 104 groups (k>=199 zeroed)
//   [104*512   ..) PWL1_32  16 kt x 8 nt                 = 128 groups
//   [232*512   ..) PW2      8 kt(K=32), 16x16 frag, cols 0..3 real
//   [240*512   ..) PWL2     8 kt(K=32), 16x16 frag, 16 cols
constexpr int PWL1_OFF = 104 * 512;
constexpr int PW2_OFF  = 232 * 512;
constexpr int PWL2_OFF = 240 * 512;   // total 248 KB <= ws

__global__ void pack_weights(const float* __restrict__ W1, const float* __restrict__ W2,
                             const float* __restrict__ Wl1, const float* __restrict__ Wl2,
                             bf16* __restrict__ ws) {
  const int gid  = blockIdx.x * blockDim.x + threadIdx.x;  // [0, 15872)
  const int lane = gid & 63;
  const int grp  = gid >> 6;        // [0, 248)
  bf16x8 v;
  if (grp < 104) {                  // PW1_32: 32x32x16 B frag: col=lane&31, k=(lane>>5)*8+j
    const int kt = grp >> 3, nt = grp & 7, n = nt * 32 + (lane & 31);
#pragma unroll
    for (int j = 0; j < 8; ++j) {
      const int k = kt * 16 + (lane >> 5) * 8 + j;
      v[j] = (k < WIN) ? (bf16)W1[k * HID + n] : (bf16)0.0f;
    }
  } else if (grp < 232) {           // PWL1_32
    const int q = grp - 104;
    const int kt = q >> 3, nt = q & 7, n = nt * 32 + (lane & 31);
#pragma unroll
    for (int j = 0; j < 8; ++j) {
      const int k = kt * 16 + (lane >> 5) * 8 + j;
      v[j] = (bf16)Wl1[k * HID + n];
    }
  } else if (grp < 240) {           // PW2: 16x16x32 frag: col=lane&15, k=(lane>>4)*8+j
    const int kt = grp - 232, m = lane & 15;
#pragma unroll
    for (int j = 0; j < 8; ++j) {
      const int k = kt * 32 + (lane >> 4) * 8 + j;
      v[j] = (m < 4) ? (bf16)W2[k * 4 + m] : (bf16)0.0f;
    }
  } else {                          // PWL2
    const int kt = grp - 240, m = lane & 15;
#pragma unroll
    for (int j = 0; j < 8; ++j) {
      const int k = kt * 32 + (lane >> 4) * 8 + j;
      v[j] = (bf16)Wl2[k * 16 + m];
    }
  }
  *reinterpret_cast<bf16x8*>(ws + (size_t)gid * 8) = v;
}

__global__ __launch_bounds__(512, 6) void fused_enc(
    const float* __restrict__ V, const float* __restrict__ b1,
    const float* __restrict__ b2, const float* __restrict__ bl1,
    const float* __restrict__ bl2, const bf16* __restrict__ ws,
    float* __restrict__ out) {
  __shared__ bf16 Vdup[8][VSTR];    // 4.6 KB: Vdup[p][q] = pad[t0-99+q+p]
  __shared__ bf16 hbuf[BT * HSTR];  // 33 KB: h_mid, then h_leaf (WAR barrier)
  // total 38528 B -> 4 blocks by LDS; 3 by regs (85-cap) -> 3 blocks/CU

  const int tid  = threadIdx.x;
  const int lane = tid & 63;
  const int w    = tid >> 6;            // wave id [0,8): owns 32-col stripe w
  const int wr   = w & 3;               // mu row group: rows wr*16 .. wr*16+15
  const int c5   = lane & 31;           // 32x32 frag col/row index
  const int hi   = lane >> 5;           // 32x32 frag k-half
  const int m    = lane & 15;           // 16x16 frag index
  const int g    = lane >> 4;           // 16x16 k-group
  const long t0  = (long)blockIdx.x * BT;

  // ---- 1. stage 8 shifted bf16 window copies ----
  for (int c = tid; c < 8 * VLEN; c += 512) {
    const int p = c / VLEN, q = c - p * VLEN;
    const long src = t0 + q + p - (T_V - 1);
    const float v = (src >= 0 && src < T_DATA) ? V[src] : 0.0f;
    Vdup[p][q] = (bf16)v;
  }
  __syncthreads();   // B0

  // A-frag element s = (rt*32 + c5) + kt*16 + hi*8 + j; s mod 8 = lane&7
  // (rt*32 is 0 mod 8) -> copy p = lane&7 gives one aligned b128 read.
  const int p  = lane & 7;
  const int qb = (c5 + hi * 8) - p;     // aligned base within Vdup row p
  const bf16* vrow = &Vdup[p][0];

  f32x16 acc0 = {}, acc1 = {};          // row-tiles: rows 0-31 and 32-63

  // ---- 2. GEMM1: h_mid(pre) = windows @ W1, 13 kt of K=16 ----
#pragma unroll
  for (int kt = 0; kt < 13; ++kt) {
    const bf16x8 b  = *reinterpret_cast<const bf16x8*>(
        ws + (size_t)(kt * 8 + w) * 512 + lane * 8);
    const bf16x8 a0 = *reinterpret_cast<const bf16x8*>(vrow + qb + kt * 16);
    const bf16x8 a1 = *reinterpret_cast<const bf16x8*>(vrow + qb + kt * 16 + 32);
    acc0 = __builtin_amdgcn_mfma_f32_32x32x16_bf16(a0, b, acc0, 0, 0, 0);
    acc1 = __builtin_amdgcn_mfma_f32_32x32x16_bf16(a1, b, acc1, 0, 0, 0);
  }

  // ---- 3. h_mid epilogue: bias+relu -> hbuf ----
  // C/D 32x32 layout: col = lane&31, row = (r&3) + 8*(r>>2) + 4*(lane>>5)
  const int   col = w * 32 + c5;
  const float bb1 = b1[col];
#pragma unroll
  for (int r = 0; r < 16; ++r) {
    const int row = (r & 3) + 8 * (r >> 2) + 4 * hi;
    hbuf[row * HSTR + col]        = (bf16)fmaxf(acc0[r] + bb1, 0.0f);
    hbuf[(row + 32) * HSTR + col] = (bf16)fmaxf(acc1[r] + bb1, 0.0f);
  }
  __syncthreads();   // B1: h_mid visible

  // ---- 4. GEMM3: h_leaf(pre) = h_mid @ Wl1, 16 kt of K=16 ----
  acc0 = (f32x16){};
  acc1 = (f32x16){};
#pragma unroll
  for (int kt = 0; kt < 16; ++kt) {
    const bf16x8 b = *reinterpret_cast<const bf16x8*>(
        ws + PWL1_OFF + (size_t)(kt * 8 + w) * 512 + lane * 8);
    const int koff = kt * 16 + hi * 8;
    const bf16x8 a0 = *reinterpret_cast<const bf16x8*>(&hbuf[c5 * HSTR + koff]);
    const bf16x8 a1 = *reinterpret_cast<const bf16x8*>(&hbuf[(32 + c5) * HSTR + koff]);
    acc0 = __builtin_amdgcn_mfma_f32_32x32x16_bf16(a0, b, acc0, 0, 0, 0);
    acc1 = __builtin_amdgcn_mfma_f32_32x32x16_bf16(a1, b, acc1, 0, 0, 0);
  }

  // ---- 4b. mu_mid: all waves compute rows wr*16..wr*16+15 (waves 0-3 store) ----
  f32x4 mu = {0.f, 0.f, 0.f, 0.f};
#pragma unroll
  for (int kt = 0; kt < 8; ++kt) {
    const bf16x8 a = *reinterpret_cast<const bf16x8*>(
        &hbuf[(wr * 16 + m) * HSTR + kt * 32 + g * 8]);
    const bf16x8 b = *reinterpret_cast<const bf16x8*>(
        ws + PW2_OFF + (size_t)kt * 512 + lane * 8);
    mu = __builtin_amdgcn_mfma_f32_16x16x32_bf16(a, b, mu, 0, 0, 0);
  }
  {
    const float b2v = (m < 4) ? b2[m] : 0.0f;
#pragma unroll
    for (int j = 0; j < 4; ++j) {       // C 16x16: col=lane&15, row=(lane>>4)*4+reg
      const long t = t0 + wr * 16 + g * 4 + j;
      if (t < T_DATA && w < 4 && m < 4) out[t * 20 + m] = mu[j] + b2v;
    }
  }
  __syncthreads();   // B2 (WAR): all h_mid reads done before h_leaf overwrite

  // ---- 5. h_leaf epilogue: bias+relu -> hbuf ----
  const float bbl = bl1[col];
#pragma unroll
  for (int r = 0; r < 16; ++r) {
    const int row = (r & 3) + 8 * (r >> 2) + 4 * hi;
    hbuf[row * HSTR + col]        = (bf16)fmaxf(acc0[r] + bbl, 0.0f);
    hbuf[(row + 32) * HSTR + col] = (bf16)fmaxf(acc1[r] + bbl, 0.0f);
  }
  __syncthreads();   // B3: h_leaf visible

  // ---- 6. mu_leaf: all waves compute rows wr*16..wr*16+15 (waves 4-7 store) ----
  mu = (f32x4){0.f, 0.f, 0.f, 0.f};
#pragma unroll
  for (int kq = 0; kq < 8; ++kq) {
    const bf16x8 a = *reinterpret_cast<const bf16x8*>(
        &hbuf[(wr * 16 + m) * HSTR + kq * 32 + g * 8]);
    const bf16x8 b = *reinterpret_cast<const bf16x8*>(
        ws + PWL2_OFF + (size_t)kq * 512 + lane * 8);
    mu = __builtin_amdgcn_mfma_f32_16x16x32_bf16(a, b, mu, 0, 0, 0);
  }
  {
    const float blv = bl2[m];
#pragma unroll
    for (int j = 0; j < 4; ++j) {
      const long t = t0 + wr * 16 + g * 4 + j;
      if (t < T_DATA && w >= 4) out[t * 20 + 4 + m] = mu[j] + blv;
    }
  }
}

extern "C" void kernel_launch(void* const* d_in, const int* in_sizes, int n_in,
                              void* d_out, int out_size, void* d_ws, size_t ws_size,
                              hipStream_t stream) {
  const float* V   = (const float*)d_in[0];
  const float* W1  = (const float*)d_in[1];
  const float* b1  = (const float*)d_in[2];
  const float* W2  = (const float*)d_in[3];
  const float* b2  = (const float*)d_in[4];
  const float* Wl1 = (const float*)d_in[5];
  const float* bl1 = (const float*)d_in[6];
  const float* Wl2 = (const float*)d_in[7];
  const float* bl2 = (const float*)d_in[8];
  bf16* ws = (bf16*)d_ws;   // needs 253952 bytes
  float* out = (float*)d_out;

  pack_weights<<<62, 256, 0, stream>>>(W1, W2, Wl1, Wl2, ws);

  const int grid = (T_DATA + BT - 1) / BT;   // 1563
  fused_enc<<<grid, 512, 0, stream>>>(V, b1, b2, bl1, bl2, ws, out);
}